// Round 2
// baseline (1127.865 us; speedup 1.0000x reference)
//
#include <hip/hip_runtime.h>
#include <hip/hip_bf16.h>

// GCN 2-layer: relu(A_hat @ relu(A_hat @ X @ W1 + b1) @ W2 + b2)
//   L1: aggregate X first (256 feats), then GEMM by W1 (+b1, relu)
//   L2: GEMM by W2 first (250 feats, padded ldc=256), then aggregate (+b2, relu)
//   Aggregation: pull-style via per-call CSR (no float atomics), wave-per-node.

#define F_IN  256
#define F_HID 512
#define F_OUT 250

// ---------------- CSR build ----------------

__global__ __launch_bounds__(256) void init_kernel(int* cnt, int* cursor, int n) {
    int i = blockIdx.x * 256 + threadIdx.x;
    if (i < n) { cnt[i] = 0; cursor[i] = 0; }
}

__global__ __launch_bounds__(256) void hist_kernel(const int* __restrict__ col, int* cnt, int E) {
    int e = blockIdx.x * 256 + threadIdx.x;
    if (e < E) atomicAdd(&cnt[col[e]], 1);
}

__global__ __launch_bounds__(256) void dinv_kernel(const int* __restrict__ cnt, float* dinv, int n) {
    int i = blockIdx.x * 256 + threadIdx.x;
    if (i < n) dinv[i] = rsqrtf((float)(cnt[i] + 1));  // +1 self loop
}

// exclusive prefix sum of cnt -> rowptr, rowptr[n] = E. Single block, shfl-based.
__global__ __launch_bounds__(1024) void scan_kernel(const int* __restrict__ cnt, int* rowptr, int n) {
    __shared__ int wsum[16];
    __shared__ int carry_s;
    int t = threadIdx.x;
    int wid = t >> 6, lane = t & 63;
    if (t == 0) carry_s = 0;
    __syncthreads();
    for (int base = 0; base < n; base += 1024) {
        int i = base + t;
        int v = (i < n) ? cnt[i] : 0;
        int s = v;  // wave inclusive scan
        #pragma unroll
        for (int off = 1; off < 64; off <<= 1) {
            int u = __shfl_up(s, off, 64);
            if (lane >= off) s += u;
        }
        if (lane == 63) wsum[wid] = s;
        __syncthreads();
        if (wid == 0 && lane < 16) {
            int ws = wsum[lane];
            #pragma unroll
            for (int off = 1; off < 16; off <<= 1) {
                int u = __shfl_up(ws, off, 64);
                if (lane >= off) ws += u;
            }
            wsum[lane] = ws;  // inclusive wave-sum scan
        }
        __syncthreads();
        int wbase = (wid == 0) ? 0 : wsum[wid - 1];
        int carry = carry_s;
        if (i < n) rowptr[i] = carry + wbase + s - v;  // exclusive
        __syncthreads();
        if (t == 1023) carry_s = carry + wbase + s;    // carry + chunk total
        __syncthreads();
    }
    if (t == 0) rowptr[n] = carry_s;
}

__global__ __launch_bounds__(256) void fill_kernel(const int* __restrict__ row, const int* __restrict__ col,
                                                   const int* __restrict__ rowptr, int* cursor,
                                                   int* csr, int E) {
    int e = blockIdx.x * 256 + threadIdx.x;
    if (e < E) {
        int c = col[e];
        int p = rowptr[c] + atomicAdd(&cursor[c], 1);
        csr[p] = row[e];
    }
}

// ---------------- aggregation: wave-per-node, float4 per lane ----------------
// out[c] = dinv[c] * ( sum_{r->c} dinv[r]*X[r] + dinv[c]*X[c] )  [+bias, relu]
// F <= 256; X rows have stride LDX (floats, mult of 4); out rows stride ldo.

template<int F, int LDX, bool BIAS_RELU>
__global__ __launch_bounds__(256) void agg_kernel(const float* __restrict__ X,
                                                  const float* __restrict__ dinv,
                                                  const int* __restrict__ rowptr,
                                                  const int* __restrict__ csr,
                                                  const float* __restrict__ bias,
                                                  float* __restrict__ out, int ldo, int n) {
    int c = blockIdx.x * 4 + (threadIdx.x >> 6);
    if (c >= n) return;
    int l = threadIdx.x & 63;
    int f0 = l * 4;                       // 0..252, 16B aligned within row
    float dc = dinv[c];

    float4 acc;
    {
        float4 v = *(const float4*)(X + (size_t)c * LDX + f0);
        acc.x = v.x * dc; acc.y = v.y * dc; acc.z = v.z * dc; acc.w = v.w * dc;
    }
    int beg = rowptr[c], end = rowptr[c + 1];
    #pragma unroll 2
    for (int j = beg; j < end; ++j) {
        int r = csr[j];
        float dr = dinv[r];
        float4 v = *(const float4*)(X + (size_t)r * LDX + f0);
        acc.x += dr * v.x; acc.y += dr * v.y; acc.z += dr * v.z; acc.w += dr * v.w;
    }
    acc.x *= dc; acc.y *= dc; acc.z *= dc; acc.w *= dc;

    float* op = out + (size_t)c * ldo + f0;
    if (BIAS_RELU) {
        float b[4];
        #pragma unroll
        for (int q = 0; q < 4; ++q) b[q] = (f0 + q < F) ? bias[f0 + q] : 0.f;
        acc.x = fmaxf(acc.x + b[0], 0.f);
        acc.y = fmaxf(acc.y + b[1], 0.f);
        acc.z = fmaxf(acc.z + b[2], 0.f);
        acc.w = fmaxf(acc.w + b[3], 0.f);
        if (f0 + 3 < F) {  // rows stride ldo=250: 8B-aligned float2 stores
            ((float2*)op)[0] = make_float2(acc.x, acc.y);
            ((float2*)op)[1] = make_float2(acc.z, acc.w);
        } else {
            float a4[4] = {acc.x, acc.y, acc.z, acc.w};
            #pragma unroll
            for (int q = 0; q < 4; ++q)
                if (f0 + q < F) op[q] = a4[q];
        }
    } else {
        *(float4*)op = acc;  // F==LDX==ldo==256, 16B aligned
    }
}

// ---------------- fp32 tiled GEMM (vector ALU; no fp32 MFMA on CDNA4) ----------------
// C[M,N] = A[M,K] @ B[K,N] (+bias, relu). 128x128 tile, BK=16, 256 thr, 8x8/thread.
// K must be a multiple of 16. BV4: B rows 16B-aligned (N%4==0) -> float4 staging.

template<bool BIAS_RELU, bool BV4>
__global__ __launch_bounds__(256) void gemm_kernel(const float* __restrict__ A,
                                                   const float* __restrict__ B,
                                                   const float* __restrict__ bias,
                                                   float* __restrict__ C,
                                                   int M, int N, int K, int ldc) {
    const int BM = 128, BN = 128, BK = 16;
    __shared__ __align__(16) float As[BK][BM + 4];
    __shared__ __align__(16) float Bs[BK][BN + 4];

    int t = threadIdx.x;
    int row0 = blockIdx.x * BM;
    int col0 = blockIdx.y * BN;
    int tm = t & 15, tn = t >> 4;

    int la_r = t >> 2;          // 0..63 (+64 second half)
    int la_c = (t & 3) * 4;     // k offset 0,4,8,12
    int lb_r = t >> 4;          // 0..15 (k)
    int lb_c = (t & 15) * 4;    // 0..60 (+64 second half)

    float acc[8][8] = {};

    for (int k0 = 0; k0 < K; k0 += BK) {
        #pragma unroll
        for (int h = 0; h < 2; ++h) {
            int r = row0 + la_r + h * 64;
            float4 v = make_float4(0.f, 0.f, 0.f, 0.f);
            if (r < M) v = *(const float4*)&A[(size_t)r * K + k0 + la_c];
            As[la_c + 0][la_r + h * 64] = v.x;
            As[la_c + 1][la_r + h * 64] = v.y;
            As[la_c + 2][la_r + h * 64] = v.z;
            As[la_c + 3][la_r + h * 64] = v.w;
        }
        #pragma unroll
        for (int h = 0; h < 2; ++h) {
            int cc = col0 + lb_c + h * 64;
            const float* bp = &B[(size_t)(k0 + lb_r) * N + cc];
            float v0 = 0.f, v1 = 0.f, v2 = 0.f, v3 = 0.f;
            if (BV4) {
                if (cc + 3 < N) { float4 u = *(const float4*)bp; v0 = u.x; v1 = u.y; v2 = u.z; v3 = u.w; }
            } else {
                // rows only 8B-aligned (e.g. N=250): float2 pairs, guarded
                if (cc + 1 < N)      { float2 u = *(const float2*)bp;       v0 = u.x; v1 = u.y; }
                else if (cc < N)     { v0 = bp[0]; }
                if (cc + 3 < N)      { float2 u = *(const float2*)(bp + 2); v2 = u.x; v3 = u.y; }
                else if (cc + 2 < N) { v2 = bp[2]; }
            }
            Bs[lb_r][lb_c + h * 64 + 0] = v0;
            Bs[lb_r][lb_c + h * 64 + 1] = v1;
            Bs[lb_r][lb_c + h * 64 + 2] = v2;
            Bs[lb_r][lb_c + h * 64 + 3] = v3;
        }
        __syncthreads();
        #pragma unroll
        for (int k = 0; k < BK; ++k) {
            float4 a0 = *(const float4*)&As[k][tm * 4];
            float4 a1 = *(const float4*)&As[k][tm * 4 + 64];
            float4 b0 = *(const float4*)&Bs[k][tn * 4];
            float4 b1 = *(const float4*)&Bs[k][tn * 4 + 64];
            float a[8] = {a0.x, a0.y, a0.z, a0.w, a1.x, a1.y, a1.z, a1.w};
            float b[8] = {b0.x, b0.y, b0.z, b0.w, b1.x, b1.y, b1.z, b1.w};
            #pragma unroll
            for (int i = 0; i < 8; ++i)
                #pragma unroll
                for (int j = 0; j < 8; ++j)
                    acc[i][j] += a[i] * b[j];
        }
        __syncthreads();
    }

    #pragma unroll
    for (int i = 0; i < 8; ++i) {
        int r = row0 + tm * 4 + (i & 3) + (i >> 2) * 64;
        if (r >= M) continue;
        #pragma unroll
        for (int jh = 0; jh < 2; ++jh) {
            int cc = col0 + tn * 4 + jh * 64;
            if (cc + 3 < N) {
                float4 v;
                float* vp = &v.x;
                #pragma unroll
                for (int q = 0; q < 4; ++q) {
                    float z = acc[i][jh * 4 + q];
                    if (BIAS_RELU) z = fmaxf(z + bias[cc + q], 0.f);
                    vp[q] = z;
                }
                *(float4*)&C[(size_t)r * ldc + cc] = v;
            } else {
                #pragma unroll
                for (int q = 0; q < 4; ++q) {
                    if (cc + q < N) {
                        float z = acc[i][jh * 4 + q];
                        if (BIAS_RELU) z = fmaxf(z + bias[cc + q], 0.f);
                        C[(size_t)r * ldc + cc + q] = z;
                    }
                }
            }
        }
    }
}

// ---------------- launch ----------------

extern "C" void kernel_launch(void* const* d_in, const int* in_sizes, int n_in,
                              void* d_out, int out_size, void* d_ws, size_t ws_size,
                              hipStream_t stream) {
    const float* x   = (const float*)d_in[0];
    const int*   ei  = (const int*)d_in[1];
    const float* W1  = (const float*)d_in[2];
    const float* b1  = (const float*)d_in[3];
    const float* W2  = (const float*)d_in[4];
    const float* b2  = (const float*)d_in[5];
    float* out = (float*)d_out;

    const int n = in_sizes[0] / F_IN;
    const int E = in_sizes[1] / 2;
    const int* row = ei;
    const int* col = ei + E;

    char* p = (char*)d_ws;
    auto alloc = [&](size_t bytes) { void* r = (void*)p; p += (bytes + 255) & ~(size_t)255; return r; };
    int*   cnt    = (int*)alloc((size_t)n * 4);
    int*   cursor = (int*)alloc((size_t)n * 4);
    int*   rowptr = (int*)alloc((size_t)(n + 1) * 4);
    int*   csr    = (int*)alloc((size_t)E * 4);
    float* dinv   = (float*)alloc((size_t)n * 4);
    float* bufA   = (float*)alloc((size_t)n * 256 * 4);  // AX, then H@W2 (padded ldc=256)
    float* bufH   = (float*)alloc((size_t)n * F_HID * 4);

    int nb_n = (n + 255) / 256;
    int nb_e = (E + 255) / 256;

    // CSR build
    init_kernel<<<nb_n, 256, 0, stream>>>(cnt, cursor, n);
    hist_kernel<<<nb_e, 256, 0, stream>>>(col, cnt, E);
    dinv_kernel<<<nb_n, 256, 0, stream>>>(cnt, dinv, n);
    scan_kernel<<<1, 1024, 0, stream>>>(cnt, rowptr, n);
    fill_kernel<<<nb_e, 256, 0, stream>>>(row, col, rowptr, cursor, csr, E);

    int nb_agg = (n + 3) / 4;

    // Layer 1: aggregate X (256 feats) -> bufA; GEMM W1 + b1 + relu -> bufH
    agg_kernel<F_IN, F_IN, false><<<nb_agg, 256, 0, stream>>>(x, dinv, rowptr, csr, nullptr, bufA, F_IN, n);
    {
        dim3 grid((n + 127) / 128, (F_HID + 127) / 128);
        gemm_kernel<true, true><<<grid, 256, 0, stream>>>(bufA, W1, b1, bufH, n, F_HID, F_IN, F_HID);
    }

    // Layer 2: GEMM W2 (padded ldc=256) -> bufA; aggregate (250 feats) + b2 + relu -> out
    {
        dim3 grid((n + 127) / 128, (F_OUT + 127) / 128);
        gemm_kernel<false, false><<<grid, 256, 0, stream>>>(bufH, W2, nullptr, bufA, n, F_OUT, F_HID, 256);
    }
    agg_kernel<F_OUT, 256, true><<<nb_agg, 256, 0, stream>>>(bufA, dinv, rowptr, csr, b2, out, F_OUT, n);
}

// Round 5
// 904.589 us; speedup vs baseline: 1.2468x; 1.2468x over previous
//
#include <hip/hip_runtime.h>
#include <hip/hip_bf16.h>

// GCN 2-layer: relu(A_hat @ relu(A_hat @ X @ W1 + b1) @ W2 + b2)
//   L1: aggregate X (256f) -> split-bf16; MFMA GEMM W1 (+b1, relu) -> split-bf16 H
//   L2: MFMA GEMM W2 -> fp32 Y (ldc=256); aggregate Y (250f) + b2 + relu
//   GEMMs: bf16 MFMA with hi/lo split precision (3 products), ~2^-16 rel error.
//   Aggregation: pull-style via per-call CSR (no float atomics), wave-per-node.

#define F_IN  256
#define F_HID 512
#define F_OUT 250

using bf16x8 = __attribute__((ext_vector_type(8))) short;
using f32x4  = __attribute__((ext_vector_type(4))) float;

__device__ __forceinline__ ushort f32_bf16_rne(float f) {
    uint u = __float_as_uint(f);
    u += 0x7FFFu + ((u >> 16) & 1u);
    return (ushort)(u >> 16);
}
__device__ __forceinline__ float bf16u_f32(ushort h) {
    return __uint_as_float(((uint)h) << 16);
}

// ---------------- CSR build ----------------

__global__ __launch_bounds__(256) void init_kernel(int* cnt, int* cursor, int n) {
    int i = blockIdx.x * 256 + threadIdx.x;
    if (i < n) { cnt[i] = 0; cursor[i] = 0; }
}

__global__ __launch_bounds__(256) void hist_kernel(const int* __restrict__ col, int* cnt, int E) {
    int e = blockIdx.x * 256 + threadIdx.x;
    if (e < E) atomicAdd(&cnt[col[e]], 1);
}

__global__ __launch_bounds__(256) void dinv_kernel(const int* __restrict__ cnt, float* dinv, int n) {
    int i = blockIdx.x * 256 + threadIdx.x;
    if (i < n) dinv[i] = rsqrtf((float)(cnt[i] + 1));  // +1 self loop
}

__global__ __launch_bounds__(1024) void scan_kernel(const int* __restrict__ cnt, int* rowptr, int n) {
    __shared__ int wsum[16];
    __shared__ int carry_s;
    int t = threadIdx.x;
    int wid = t >> 6, lane = t & 63;
    if (t == 0) carry_s = 0;
    __syncthreads();
    for (int base = 0; base < n; base += 1024) {
        int i = base + t;
        int v = (i < n) ? cnt[i] : 0;
        int s = v;
        #pragma unroll
        for (int off = 1; off < 64; off <<= 1) {
            int u = __shfl_up(s, off, 64);
            if (lane >= off) s += u;
        }
        if (lane == 63) wsum[wid] = s;
        __syncthreads();
        if (wid == 0 && lane < 16) {
            int ws = wsum[lane];
            #pragma unroll
            for (int off = 1; off < 16; off <<= 1) {
                int u = __shfl_up(ws, off, 64);
                if (lane >= off) ws += u;
            }
            wsum[lane] = ws;
        }
        __syncthreads();
        int wbase = (wid == 0) ? 0 : wsum[wid - 1];
        int carry = carry_s;
        if (i < n) rowptr[i] = carry + wbase + s - v;
        __syncthreads();
        if (t == 1023) carry_s = carry + wbase + s;
        __syncthreads();
    }
    if (t == 0) rowptr[n] = carry_s;
}

__global__ __launch_bounds__(256) void fill_kernel(const int* __restrict__ row, const int* __restrict__ col,
                                                   const int* __restrict__ rowptr, int* cursor,
                                                   int* csr, int E) {
    int e = blockIdx.x * 256 + threadIdx.x;
    if (e < E) {
        int c = col[e];
        int p = rowptr[c] + atomicAdd(&cursor[c], 1);
        csr[p] = row[e];
    }
}

// ---------------- W transpose + split:  W[K][N] fp32 -> WT_hi/lo [N][K] bf16 ----------------
// Scalar global loads: W rows may be only 4B-aligned (N=250). Tiny kernel, runs once.

__global__ __launch_bounds__(256) void wsplit_kernel(const float* __restrict__ W,
                                                     ushort* __restrict__ WThi, ushort* __restrict__ WTlo,
                                                     int K, int N) {
    __shared__ float tile[32][33];
    int t = threadIdx.x;
    int k0 = blockIdx.x * 32, n0 = blockIdx.y * 32;
    int r = t >> 3, c = (t & 7) * 4;
    #pragma unroll
    for (int q = 0; q < 4; ++q) {
        float z = 0.f;
        if (n0 + c + q < N) z = W[(size_t)(k0 + r) * N + n0 + c + q];
        tile[r][c + q] = z;
    }
    __syncthreads();
    int nr = t >> 3, kq = (t & 7) * 4;
    int gn = n0 + nr;
    if (gn < N) {
        ushort4 h4, l4;
        ushort* hp = &h4.x; ushort* lp = &l4.x;
        #pragma unroll
        for (int q = 0; q < 4; ++q) {
            float z = tile[kq + q][nr];
            ushort h = f32_bf16_rne(z);
            hp[q] = h;
            lp[q] = f32_bf16_rne(z - bf16u_f32(h));
        }
        *(ushort4*)&WThi[(size_t)gn * K + k0 + kq] = h4;
        *(ushort4*)&WTlo[(size_t)gn * K + k0 + kq] = l4;
    }
}

// ---------------- aggregation: wave-per-node, float4 per lane ----------------
// out[c] = dinv[c] * ( sum_{r->c} dinv[r]*X[r] + dinv[c]*X[c] )  [+bias/relu | split-bf16]

template<int F, int LDX, bool BIAS_RELU, bool SPLIT_OUT>
__global__ __launch_bounds__(256) void agg_kernel(const float* __restrict__ X,
                                                  const float* __restrict__ dinv,
                                                  const int* __restrict__ rowptr,
                                                  const int* __restrict__ csr,
                                                  const float* __restrict__ bias,
                                                  float* __restrict__ out,
                                                  ushort* __restrict__ outHi, ushort* __restrict__ outLo,
                                                  int ldo, int n) {
    int c = blockIdx.x * 4 + (threadIdx.x >> 6);
    if (c >= n) return;
    int l = threadIdx.x & 63;
    int f0 = l * 4;
    float dc = dinv[c];

    float4 acc;
    {
        float4 v = *(const float4*)(X + (size_t)c * LDX + f0);
        acc.x = v.x * dc; acc.y = v.y * dc; acc.z = v.z * dc; acc.w = v.w * dc;
    }
    int beg = rowptr[c], end = rowptr[c + 1];
    #pragma unroll 4
    for (int j = beg; j < end; ++j) {
        int r = csr[j];
        float dr = dinv[r];
        float4 v = *(const float4*)(X + (size_t)r * LDX + f0);
        acc.x += dr * v.x; acc.y += dr * v.y; acc.z += dr * v.z; acc.w += dr * v.w;
    }
    acc.x *= dc; acc.y *= dc; acc.z *= dc; acc.w *= dc;

    if (SPLIT_OUT) {
        ushort4 h4, l4;
        float a4[4] = {acc.x, acc.y, acc.z, acc.w};
        ushort* hp = &h4.x; ushort* lp = &l4.x;
        #pragma unroll
        for (int q = 0; q < 4; ++q) {
            ushort h = f32_bf16_rne(a4[q]);
            hp[q] = h;
            lp[q] = f32_bf16_rne(a4[q] - bf16u_f32(h));
        }
        *(ushort4*)(outHi + (size_t)c * F + f0) = h4;
        *(ushort4*)(outLo + (size_t)c * F + f0) = l4;
        return;
    }

    float* op = out + (size_t)c * ldo + f0;
    if (BIAS_RELU) {
        float b[4];
        #pragma unroll
        for (int q = 0; q < 4; ++q) b[q] = (f0 + q < F) ? bias[f0 + q] : 0.f;
        acc.x = fmaxf(acc.x + b[0], 0.f);
        acc.y = fmaxf(acc.y + b[1], 0.f);
        acc.z = fmaxf(acc.z + b[2], 0.f);
        acc.w = fmaxf(acc.w + b[3], 0.f);
        if (f0 + 3 < F) {
            ((float2*)op)[0] = make_float2(acc.x, acc.y);
            ((float2*)op)[1] = make_float2(acc.z, acc.w);
        } else {
            float a4[4] = {acc.x, acc.y, acc.z, acc.w};
            #pragma unroll
            for (int q = 0; q < 4; ++q)
                if (f0 + q < F) op[q] = a4[q];
        }
    } else {
        *(float4*)op = acc;
    }
}

// ---------------- MFMA split-bf16 GEMM ----------------
// C[M,N] = (Ahi+Alo)[M,K] @ (Bhi+Blo)^T-stored[N,K]   (3-product split)
// BM=BN=128, BK=32, 256 thr (4 waves, 2x2), per-wave 64x64 = 4x4 frags of 16x16x32.
// SPLIT_OUT: +bias, relu, emit split-bf16 (ld = N). else: fp32 out, ldc param.

template<bool SPLIT_OUT>
__global__ __launch_bounds__(256) void gemm_mfma(const ushort* __restrict__ Ahi, const ushort* __restrict__ Alo,
                                                 const ushort* __restrict__ Bhi, const ushort* __restrict__ Blo,
                                                 const float* __restrict__ bias,
                                                 float* __restrict__ Cf,
                                                 ushort* __restrict__ Chi, ushort* __restrict__ Clo,
                                                 int M, int N, int K, int ldc) {
    __shared__ ushort As_hi[128][40];   // 80B rows: 16B-aligned, <=2-way bank alias
    __shared__ ushort As_lo[128][40];
    __shared__ ushort Bs_hi[128][40];
    __shared__ ushort Bs_lo[128][40];

    int t = threadIdx.x;
    int row0 = blockIdx.x * 128;
    int col0 = blockIdx.y * 128;
    int lane = t & 63;
    int w = t >> 6;
    int wr = w >> 1, wc = w & 1;       // wave 64x64 sub-tile
    int lr = lane & 15, lg = lane >> 4;

    int srow = t >> 2;                 // staging: 64 rows per pass
    int soct = (t & 3) * 8;            // k-octet within BK=32

    f32x4 acc[4][4];
    #pragma unroll
    for (int i = 0; i < 4; ++i)
        #pragma unroll
        for (int j = 0; j < 4; ++j)
            acc[i][j] = (f32x4){0.f, 0.f, 0.f, 0.f};

    for (int k0 = 0; k0 < K; k0 += 32) {
        #pragma unroll
        for (int h = 0; h < 2; ++h) {
            int r = srow + h * 64;
            int4 zero = make_int4(0, 0, 0, 0);
            int ga = row0 + r;
            int4 vh = zero, vl = zero;
            if (ga < M) {
                vh = *(const int4*)(Ahi + (size_t)ga * K + k0 + soct);
                vl = *(const int4*)(Alo + (size_t)ga * K + k0 + soct);
            }
            *(int4*)&As_hi[r][soct] = vh;
            *(int4*)&As_lo[r][soct] = vl;
            int gb = col0 + r;
            int4 wh = zero, wl = zero;
            if (gb < N) {
                wh = *(const int4*)(Bhi + (size_t)gb * K + k0 + soct);
                wl = *(const int4*)(Blo + (size_t)gb * K + k0 + soct);
            }
            *(int4*)&Bs_hi[r][soct] = wh;
            *(int4*)&Bs_lo[r][soct] = wl;
        }
        __syncthreads();

        bf16x8 ah[4], al[4], bh[4], bl[4];
        #pragma unroll
        for (int mi = 0; mi < 4; ++mi) {
            ah[mi] = *(const bf16x8*)&As_hi[wr * 64 + mi * 16 + lr][lg * 8];
            al[mi] = *(const bf16x8*)&As_lo[wr * 64 + mi * 16 + lr][lg * 8];
        }
        #pragma unroll
        for (int ni = 0; ni < 4; ++ni) {
            bh[ni] = *(const bf16x8*)&Bs_hi[wc * 64 + ni * 16 + lr][lg * 8];
            bl[ni] = *(const bf16x8*)&Bs_lo[wc * 64 + ni * 16 + lr][lg * 8];
        }
        #pragma unroll
        for (int mi = 0; mi < 4; ++mi)
            #pragma unroll
            for (int ni = 0; ni < 4; ++ni) {
                acc[mi][ni] = __builtin_amdgcn_mfma_f32_16x16x32_bf16(ah[mi], bh[ni], acc[mi][ni], 0, 0, 0);
                acc[mi][ni] = __builtin_amdgcn_mfma_f32_16x16x32_bf16(ah[mi], bl[ni], acc[mi][ni], 0, 0, 0);
                acc[mi][ni] = __builtin_amdgcn_mfma_f32_16x16x32_bf16(al[mi], bh[ni], acc[mi][ni], 0, 0, 0);
            }
        __syncthreads();
    }

    // epilogue: D lane map (verified): row=(lane>>4)*4+reg, col=lane&15
    #pragma unroll
    for (int mi = 0; mi < 4; ++mi) {
        int rbase = row0 + wr * 64 + mi * 16 + lg * 4;
        #pragma unroll
        for (int ni = 0; ni < 4; ++ni) {
            int cg = col0 + wc * 64 + ni * 16 + lr;
            f32x4 a = acc[mi][ni];
            if (SPLIT_OUT) {
                float bia = bias[cg];
                #pragma unroll
                for (int r = 0; r < 4; ++r) {
                    int rg = rbase + r;
                    if (rg < M) {
                        float z = fmaxf(a[r] + bia, 0.f);
                        ushort h = f32_bf16_rne(z);
                        Chi[(size_t)rg * N + cg] = h;
                        Clo[(size_t)rg * N + cg] = f32_bf16_rne(z - bf16u_f32(h));
                    }
                }
            } else {
                if (cg < N) {
                    #pragma unroll
                    for (int r = 0; r < 4; ++r) {
                        int rg = rbase + r;
                        if (rg < M) Cf[(size_t)rg * ldc + cg] = a[r];
                    }
                }
            }
        }
    }
}

// ---------------- launch ----------------

extern "C" void kernel_launch(void* const* d_in, const int* in_sizes, int n_in,
                              void* d_out, int out_size, void* d_ws, size_t ws_size,
                              hipStream_t stream) {
    const float* x   = (const float*)d_in[0];
    const int*   ei  = (const int*)d_in[1];
    const float* W1  = (const float*)d_in[2];
    const float* b1  = (const float*)d_in[3];
    const float* W2  = (const float*)d_in[4];
    const float* b2  = (const float*)d_in[5];
    float* out = (float*)d_out;

    const int n = in_sizes[0] / F_IN;
    const int E = in_sizes[1] / 2;
    const int* row = ei;
    const int* col = ei + E;

    char* p = (char*)d_ws;
    auto alloc = [&](size_t bytes) { void* r = (void*)p; p += (bytes + 255) & ~(size_t)255; return r; };
    int*    cnt    = (int*)alloc((size_t)n * 4);
    int*    cursor = (int*)alloc((size_t)n * 4);
    int*    rowptr = (int*)alloc((size_t)(n + 1) * 4);
    int*    csr    = (int*)alloc((size_t)E * 4);
    float*  dinv   = (float*)alloc((size_t)n * 4);
    ushort* Ahi    = (ushort*)alloc((size_t)n * F_IN * 2);   // agg1 out (hi)
    ushort* Alo    = (ushort*)alloc((size_t)n * F_IN * 2);   // agg1 out (lo)
    ushort* Hhi    = (ushort*)alloc((size_t)n * F_HID * 2);  // gemm1 out (hi)
    ushort* Hlo    = (ushort*)alloc((size_t)n * F_HID * 2);
    ushort* W1Thi  = (ushort*)alloc((size_t)F_HID * F_IN * 2);
    ushort* W1Tlo  = (ushort*)alloc((size_t)F_HID * F_IN * 2);
    ushort* W2Thi  = (ushort*)alloc((size_t)F_OUT * F_HID * 2);
    ushort* W2Tlo  = (ushort*)alloc((size_t)F_OUT * F_HID * 2);
    float*  bufY   = (float*)Ahi;   // gemm2 out [n][256]; aliases Ahi+Alo (dead by then)

    int nb_n = (n + 255) / 256;
    int nb_e = (E + 255) / 256;

    // CSR build
    init_kernel<<<nb_n, 256, 0, stream>>>(cnt, cursor, n);
    hist_kernel<<<nb_e, 256, 0, stream>>>(col, cnt, E);
    dinv_kernel<<<nb_n, 256, 0, stream>>>(cnt, dinv, n);
    scan_kernel<<<1, 1024, 0, stream>>>(cnt, rowptr, n);
    fill_kernel<<<nb_e, 256, 0, stream>>>(row, col, rowptr, cursor, csr, E);

    // weight transpose+split
    {
        dim3 g1(F_IN / 32, F_HID / 32);
        wsplit_kernel<<<g1, 256, 0, stream>>>(W1, W1Thi, W1Tlo, F_IN, F_HID);
        dim3 g2(F_HID / 32, (F_OUT + 31) / 32);
        wsplit_kernel<<<g2, 256, 0, stream>>>(W2, W2Thi, W2Tlo, F_HID, F_OUT);
    }

    int nb_agg = (n + 3) / 4;

    // L1: aggregate X -> split bf16
    agg_kernel<F_IN, F_IN, false, true><<<nb_agg, 256, 0, stream>>>(
        x, dinv, rowptr, csr, nullptr, nullptr, Ahi, Alo, F_IN, n);
    // GEMM1: (AX) @ W1 + b1, relu -> split bf16 H
    {
        dim3 grid((n + 127) / 128, F_HID / 128);
        gemm_mfma<true><<<grid, 256, 0, stream>>>(Ahi, Alo, W1Thi, W1Tlo, b1,
                                                  nullptr, Hhi, Hlo, n, F_HID, F_IN, F_HID);
    }
    // GEMM2: H @ W2 -> fp32 Y (ldc=256)
    {
        dim3 grid((n + 127) / 128, (F_OUT + 127) / 128);
        gemm_mfma<false><<<grid, 256, 0, stream>>>(Hhi, Hlo, W2Thi, W2Tlo, nullptr,
                                                   bufY, nullptr, nullptr, n, F_OUT, F_HID, 256);
    }
    // L2: aggregate Y + b2, relu -> out
    agg_kernel<F_OUT, 256, true, false><<<nb_agg, 256, 0, stream>>>(
        bufY, dinv, rowptr, csr, b2, out, nullptr, nullptr, F_OUT, n);
}